// Round 3
// baseline (494.144 us; speedup 1.0000x reference)
//
#include <hip/hip_runtime.h>
#include <math.h>

// Problem constants
#define B_ 2
#define N_ 4096
#define C_ 256
#define H_ 4
#define DH_ 64
#define EPS_ 1e-6f
// 1/sqrt(DH) * log2(e), folded into Wq/bq so P = exp2(s) directly
#define SCALE_Q_ 0.18033688011112042f

typedef short bf16x8 __attribute__((ext_vector_type(8)));   // 8 bf16 in 4 VGPRs
typedef short bf16x4v __attribute__((ext_vector_type(4)));  // 4 bf16 in 2 VGPRs
typedef float f32x4 __attribute__((ext_vector_type(4)));
typedef int i32x4 __attribute__((ext_vector_type(4)));

// Only HW-verified gfx950 builtins, called directly — NO __has_builtin (host
// pass returns false for target builtins) and NO inline-asm trans ops (R6).
// REGISTER RULE (R8, R11): at launch_bounds(512,4) the unified file splits
// 64 arch VGPR + 64 AGPR — only attnout's state fits.
// PREFETCH RULE (R16, new): plain C++ register prefetch gets SUNK by the
// compiler to the consume point (R2: colstats VGPR=36 proved it) — software
// pipelining must use side-effecting ops (global_load_lds) the compiler
// cannot reorder/sink.
#define MFMA32(a, b, c) __builtin_amdgcn_mfma_f32_16x16x32_bf16(a, b, c, 0, 0, 0)
#define FAST_EXP2(x) __builtin_amdgcn_exp2f(x)   // v_exp_f32, hazard-aware

// Direct global->LDS (16B/lane). LDS dest is wave-uniform base + lane*16
// (m104): dest must be LINEAR in lane order; swizzle is applied by
// pre-swizzling the per-lane GLOBAL source address (m173 / rule #21).
typedef const unsigned int __attribute__((address_space(1)))* gptr_as1;
typedef unsigned int __attribute__((address_space(3)))* lptr_as3;
#define GLL16(gp, lp)                                                   \
  __builtin_amdgcn_global_load_lds(                                     \
      (gptr_as1)(unsigned long long)(const void*)(gp),                  \
      (lptr_as3)(unsigned int)(unsigned long long)(const void*)(lp),    \
      16, 0, 0)

__device__ __forceinline__ unsigned short f2bf(float x) {
  unsigned int u = __float_as_uint(x);
  return (unsigned short)((u + 0x7FFFu + ((u >> 16) & 1u)) >> 16);  // RNE
}
__device__ __forceinline__ float bf2f(unsigned short u) {
  return __uint_as_float(((unsigned int)u) << 16);
}
// Pack two floats to two bf16 (round-half-up) in one v_perm_b32.
__device__ __forceinline__ int pack2bf(float lo, float hi) {
  return (int)__builtin_amdgcn_perm(__float_as_uint(hi) + 0x8000u,
                                    __float_as_uint(lo) + 0x8000u, 0x07060302u);
}

// ---------------------------------------------------------------------------
// Kernel 1: h16 = bf16(LayerNorm(x + pos) * g + b)
// Wave-per-row: float4 loads, pure shuffle reduce, no LDS/barriers. grid 2048.
// ---------------------------------------------------------------------------
__global__ __launch_bounds__(256) void ln_kernel(
    const float* __restrict__ x, const float* __restrict__ pos,
    const float* __restrict__ g, const float* __restrict__ beta,
    unsigned short* __restrict__ h16) {
  const int w = threadIdx.x >> 6, lane = threadIdx.x & 63;
  const int row = blockIdx.x * 4 + w;
  const float4 xv = *(const float4*)&x[row * C_ + lane * 4];
  const float4 pv = *(const float4*)&pos[row * C_ + lane * 4];
  float4 v = {xv.x + pv.x, xv.y + pv.y, xv.z + pv.z, xv.w + pv.w};
  float s = v.x + v.y + v.z + v.w;
  s += __shfl_xor(s, 1);  s += __shfl_xor(s, 2);  s += __shfl_xor(s, 4);
  s += __shfl_xor(s, 8);  s += __shfl_xor(s, 16); s += __shfl_xor(s, 32);
  const float mu = s * (1.0f / C_);
  float4 d = {v.x - mu, v.y - mu, v.z - mu, v.w - mu};
  float q = d.x * d.x + d.y * d.y + d.z * d.z + d.w * d.w;
  q += __shfl_xor(q, 1);  q += __shfl_xor(q, 2);  q += __shfl_xor(q, 4);
  q += __shfl_xor(q, 8);  q += __shfl_xor(q, 16); q += __shfl_xor(q, 32);
  const float rs = rsqrtf(q * (1.0f / C_) + EPS_);
  const float4 g4 = *(const float4*)&g[lane * 4];
  const float4 b4 = *(const float4*)&beta[lane * 4];
  bf16x4v o;
  o[0] = (short)f2bf(d.x * rs * g4.x + b4.x);
  o[1] = (short)f2bf(d.y * rs * g4.y + b4.y);
  o[2] = (short)f2bf(d.z * rs * g4.z + b4.z);
  o[3] = (short)f2bf(d.w * rs * g4.w + b4.w);
  *(bf16x4v*)&h16[row * C_ + lane * 4] = o;
}

// ---------------------------------------------------------------------------
// Kernel 2: weight transpose+cast to bf16 B-frag layout [n][k].
// ---------------------------------------------------------------------------
__global__ __launch_bounds__(256) void wconv_kernel(
    const float* __restrict__ Wq, const float* __restrict__ Wk,
    const float* __restrict__ Wv, const float* __restrict__ Wo,
    unsigned short* __restrict__ W3T, unsigned short* __restrict__ WoT) {
  const int base = blockIdx.x * 2048;
#pragma unroll
  for (int p = 0; p < 8; p++) {
    const int idx = base + p * 256 + threadIdx.x;
    if (idx < 196608) {
      const int m = idx >> 14;           // 0..11
      const int rem = idx & 16383;
      const int c = rem >> 6, d = rem & 63;
      const int h = m / 3, kind = m - h * 3;
      const float* W = kind == 0 ? Wq : kind == 1 ? Wk : Wv;
      float v = W[h * 16384 + rem];
      if (kind == 0) v *= SCALE_Q_;
      W3T[(h * 192 + kind * 64 + d) * 256 + c] = f2bf(v);
    } else {
      const int widx = idx - 196608;     // < 65536
      const int k = widx >> 8, n = widx & 255;
      WoT[n * 256 + k] = f2bf(Wo[widx]);
    }
  }
}

// ---------------------------------------------------------------------------
// Kernel 3 (MFMA): q/k/v projections.  q16,k16: [bh][n][64]; vT16: [bh][64][N]
// 64-row tiles, grid (128, H) = 512 blocks (2/CU). Wave w owns 16 rows.
// ---------------------------------------------------------------------------
__global__ __launch_bounds__(256) void qkv_kernel(
    const unsigned short* __restrict__ h16, const unsigned short* __restrict__ W3T,
    const float* __restrict__ bq, const float* __restrict__ bk,
    const float* __restrict__ bv,
    unsigned short* __restrict__ q16, unsigned short* __restrict__ k16,
    unsigned short* __restrict__ vT16) {
  const int rt = blockIdx.x;
  const int hh = blockIdx.y;
  const int t = threadIdx.x;
  const int w = t >> 6, lane = t & 63, c = lane & 15, quad = lane >> 4;
  __shared__ unsigned short Hs[64 * 64];    // 8 KB
  __shared__ unsigned short Bs[192 * 64];   // 24 KB
  const int row0 = rt * 64;

  f32x4 acc[12];
#pragma unroll
  for (int nt = 0; nt < 12; nt++) acc[nt] = (f32x4){0.f, 0.f, 0.f, 0.f};

  for (int kt = 0; kt < C_; kt += 64) {
    __syncthreads();
#pragma unroll
    for (int p = 0; p < 2; p++) {
      const int e = t + p * 256;
      const int row = e >> 3, ch = e & 7;
      *(bf16x8*)&Hs[row * 64 + ((ch ^ (row & 7)) * 8)] =
          *(const bf16x8*)&h16[(size_t)(row0 + row) * C_ + kt + ch * 8];
    }
#pragma unroll
    for (int p = 0; p < 6; p++) {
      const int e = t + p * 256;
      const int row = e >> 3, ch = e & 7;
      *(bf16x8*)&Bs[row * 64 + ((ch ^ (row & 7)) * 8)] =
          *(const bf16x8*)&W3T[(size_t)(hh * 192 + row) * C_ + kt + ch * 8];
    }
    __syncthreads();
#pragma unroll
    for (int kh = 0; kh < 2; kh++) {
      const int i = w * 16 + c;
      bf16x8 a = *(const bf16x8*)&Hs[i * 64 + (((kh * 4 + quad) ^ (i & 7)) * 8)];
#pragma unroll
      for (int nt = 0; nt < 12; nt++) {
        const int n = nt * 16 + c;
        bf16x8 b = *(const bf16x8*)&Bs[n * 64 + (((kh * 4 + quad) ^ (n & 7)) * 8)];
        acc[nt] = MFMA32(a, b, acc[nt]);
      }
    }
  }
#pragma unroll
  for (int nt = 0; nt < 12; nt++) {
    const int kind = nt >> 2;
    const int col = (nt & 3) * 16 + c;
    const float bias = kind == 0 ? bq[hh * 64 + col] * SCALE_Q_
                     : kind == 1 ? bk[hh * 64 + col] : bv[hh * 64 + col];
#pragma unroll
    for (int r = 0; r < 4; r++) {
      const int gr = row0 + w * 16 + quad * 4 + r;
      const int b = gr >> 12, n = gr & (N_ - 1);
      const size_t bh = (size_t)(b * H_ + hh);
      const unsigned short val = f2bf(acc[nt][r] + bias);
      if (kind == 0)      q16[(bh * N_ + n) * DH_ + col] = val;
      else if (kind == 1) k16[(bh * N_ + n) * DH_ + col] = val;
      else                vT16[(bh * DH_ + col) * N_ + n] = val;
    }
  }
}

// ---------------------------------------------------------------------------
// Kernel 4 (MFMA): l_j = sum_i exp2(s~_ij); vT16 *= 1/l in place.
// R16 rewrite: gll-staged, BARRIER-FREE, 64 j-cols/block.
//   - R2 failure: plain-C++ reg prefetch was sunk by the compiler (VGPR=36)
//     -> serial L2 latency. Fix: global_load_lds double-buffer + counted
//     vmcnt(2) — side-effecting, cannot be sunk (attnout's proven staging).
//   - Each wave consumes only rows it stages -> LDS buffers are WAVE-PRIVATE
//     -> zero s_barrier in the main loop.
//   - 64 j/block (ka[4][2]) halves redundant Q reads: L2 traffic 512->256MB
//     (~7.4us floor), VALU/trans floor ~8-10us binding.
// grid 512 (bh = blk&7, 64 j-cols) x 512 thr -> 2 blocks/CU, 16 waves/CU.
// ---------------------------------------------------------------------------
__global__ __launch_bounds__(512, 4) void colstats_kernel(
    const unsigned short* __restrict__ q16, const unsigned short* __restrict__ k16,
    unsigned short* __restrict__ vT16) {
  const int blk = blockIdx.x;
  const int bh = blk & 7;
  const int j0 = (blk >> 3) * 64;
  const int t = threadIdx.x;
  const int w = t >> 6, lane = t & 63, c = lane & 15, quad = lane >> 4;
  // Wave-private Q staging: 2 bufs x 8 waves x 1024 u16 (16 rows x 64 d,
  // swizzle slot = ch ^ (row&7)).
  __shared__ __align__(16) unsigned short Qb[2 * 8 * 1024];   // 32 KB
  __shared__ float Lp[8][64];
  __shared__ float ilv[64];

  // K A-frags for 64 j: rows j0 + jb*16 + c, k-halves 0/32.
  bf16x8 ka[4][2];
#pragma unroll
  for (int jb = 0; jb < 4; jb++) {
    const size_t kb = ((size_t)bh * N_ + j0 + jb * 16 + c) * DH_;
    ka[jb][0] = *(const bf16x8*)&k16[kb + quad * 8];
    ka[jb][1] = *(const bf16x8*)&k16[kb + 32 + quad * 8];
  }

  // Pre-swizzled gll source: lane l -> row_l = l>>3 (0..7), slot = l&7,
  // content chunk ch = slot ^ row_l (row&7 == row_l since w*16 % 8 == 0).
  // Second seg (+8 rows): same XOR -> just +512 u16.
  const int rl = lane >> 3, sl = lane & 7;
  const unsigned short* gQ =
      q16 + ((size_t)bh * N_ + w * 16 + rl) * DH_ + ((sl ^ rl) * 8);
  const int woff = w * 1024;           // wave's u16 offset within a buffer

  f32x4 lsum[4];
#pragma unroll
  for (int jb = 0; jb < 4; jb++) lsum[jb] = (f32x4){0.f, 0.f, 0.f, 0.f};

  // Prologue: stage tile 0 (rows w*16..+15 of i-block 0) into buf0.
  GLL16(gQ, Qb + woff);  GLL16(gQ + 512, Qb + woff + 512);
  gQ += 128 * DH_;

  for (int i0 = 0; i0 < N_; i0 += 256) {
#pragma unroll
    for (int hf = 0; hf < 2; hf++) {       // literal cur/nxt after unroll
      const int cur = hf, nxt = hf ^ 1;
      // Prefetch next 128-i block (final round over-reads adjacent
      // allocated workspace — never consumed).
      GLL16(gQ, Qb + nxt * 8192 + woff);
      GLL16(gQ + 512, Qb + nxt * 8192 + woff + 512);
      gQ += 128 * DH_;
      // Wave-private: wait own 2 oldest (cur landed), 2 newest in flight.
      asm volatile("s_waitcnt vmcnt(2)" ::: "memory");
      const unsigned short* Qs = Qb + cur * 8192 + woff;
      bf16x8 qf0 = *(const bf16x8*)&Qs[c * 64 + ((quad ^ (c & 7)) * 8)];
      bf16x8 qf1 = *(const bf16x8*)&Qs[c * 64 + (((4 + quad) ^ (c & 7)) * 8)];
#pragma unroll
      for (int jb = 0; jb < 4; jb++) {
        f32x4 s = {0.f, 0.f, 0.f, 0.f};
        s = MFMA32(ka[jb][0], qf0, s);
        s = MFMA32(ka[jb][1], qf1, s);
#pragma unroll
        for (int r = 0; r < 4; r++) lsum[jb][r] += FAST_EXP2(s[r]);
      }
    }
  }
  // Reduce over the 16 c-lanes (i-rows within wave), then over 8 waves.
#pragma unroll
  for (int jb = 0; jb < 4; jb++) {
#pragma unroll
    for (int r = 0; r < 4; r++) {
      float s = lsum[jb][r];
      s += __shfl_xor(s, 1); s += __shfl_xor(s, 2);
      s += __shfl_xor(s, 4); s += __shfl_xor(s, 8);
      if (c == 0) Lp[w][jb * 16 + quad * 4 + r] = s;
    }
  }
  __syncthreads();   // full drain: also retires the tail in-flight glls
  if (t < 64)
    ilv[t] = 1.0f / (Lp[0][t] + Lp[1][t] + Lp[2][t] + Lp[3][t] +
                     Lp[4][t] + Lp[5][t] + Lp[6][t] + Lp[7][t]);
  __syncthreads();
  // Scale this block's private 64-col vT16 slice in place: V~ = invl_j * V
  {
    const int d = t >> 3, ch = t & 7;
    const size_t addr = ((size_t)bh * DH_ + d) * N_ + j0 + ch * 8;
    bf16x8 v = *(const bf16x8*)&vT16[addr];
#pragma unroll
    for (int jj = 0; jj < 8; jj++)
      v[jj] = (short)f2bf(bf2f((unsigned short)v[jj]) * ilv[ch * 8 + jj]);
    *(bf16x8*)&vT16[addr] = v;
  }
}

// ---------------------------------------------------------------------------
// Kernel 5 (MFMA): O[i,d] = sum_j exp2(s~_ij) * V~[j,d]
// R14 staging (gll double-buffer, counted vmcnt(4), raw barriers, setprio) +
// R15 x2 unroll (literal LDS bases).
// grid 512 x 512 thr (8 waves), launch_bounds(512,4) -> 16 waves/CU.
// ---------------------------------------------------------------------------
__global__ __launch_bounds__(512, 4) void attnout_kernel(
    const unsigned short* __restrict__ q16, const unsigned short* __restrict__ k16,
    const unsigned short* __restrict__ vT16, unsigned short* __restrict__ ob16) {
  const int blk = blockIdx.x;
  const int bh = blk & 7;
  const int bb = bh >> 2, hh = bh & 3;
  const int i0 = (blk >> 3) * 64;
  const int t = threadIdx.x;
  const int w = t >> 6, lane = t & 63, c = lane & 15, quad = lane >> 4;
  const int iw = w >> 2;           // 0..1: 32-i half
  const int jw = w & 3;            // 0..3: 32-j window of the 128-j stage

  // Double buffer: buf b at u16 offset b*16384: Ks [128 j][64 d] | Vs [64 d][128 j]
  __shared__ __align__(16) char smem[65536];
  unsigned short* S16 = (unsigned short*)smem;
  float* Rf = (float*)smem;        // epilogue reduce: 4 x 8KB regions

  // Q B-frags: rows i = i0 + iw*32 + ib*16 + c
  bf16x8 qa[2][2];
#pragma unroll
  for (int ib = 0; ib < 2; ib++) {
    const size_t qb = ((size_t)bh * N_ + i0 + iw * 32 + ib * 16 + c) * DH_;
    qa[ib][0] = *(const bf16x8*)&q16[qb + quad * 8];
    qa[ib][1] = *(const bf16x8*)&q16[qb + 32 + quad * 8];
  }

  // Pre-swizzled gll source addresses (rule #21: linear LDS dest, inverse-
  // swizzled global source, swizzled read).
  const int krow  = w * 16 + (lane >> 3);
  const int kch   = (lane & 7) ^ (((krow >> 2) & 7) ^ (krow & 3));
  const int krow2 = krow + 8;
  const int kch2  = (lane & 7) ^ (((krow2 >> 2) & 7) ^ (krow2 & 3));
  const unsigned short* gK  = k16 + ((size_t)bh * N_ + krow ) * DH_ + kch  * 8;
  const unsigned short* gK2 = k16 + ((size_t)bh * N_ + krow2) * DH_ + kch2 * 8;
  const int vd   = w * 8 + (lane >> 4);
  const int vch  = (lane & 15) ^ (vd & 15);
  const int vd2  = vd + 4;
  const int vch2 = (lane & 15) ^ (vd2 & 15);
  const unsigned short* gV  = vT16 + ((size_t)bh * DH_ + vd ) * N_ + vch  * 8;
  const unsigned short* gV2 = vT16 + ((size_t)bh * DH_ + vd2) * N_ + vch2 * 8;
  const int ldsKo = w * 1024;          // u16 offset of wave's K seg in buffer
  const int ldsVo = 8192 + w * 1024;   // u16 offset of wave's V seg in buffer

  f32x4 of[2][4];
#pragma unroll
  for (int ib = 0; ib < 2; ib++)
#pragma unroll
    for (int dt = 0; dt < 4; dt++) of[ib][dt] = (f32x4){0.f, 0.f, 0.f, 0.f};

  // Prologue: stage tile 0 into buf0 (4 glls -> vmcnt outstanding = 4).
  GLL16(gK,  S16 + ldsKo);       GLL16(gK2, S16 + ldsKo + 512);
  GLL16(gV,  S16 + ldsVo);       GLL16(gV2, S16 + ldsVo + 512);
  gK += 128 * DH_; gK2 += 128 * DH_; gV += 128; gV2 += 128;

  for (int jt = 0; jt < N_; jt += 256) {
#pragma unroll
    for (int half = 0; half < 2; half++) {   // half -> literal cur after unroll
      const int cur = half, nxt = half ^ 1;
      GLL16(gK,  S16 + nxt * 16384 + ldsKo);
      GLL16(gK2, S16 + nxt * 16384 + ldsKo + 512);
      GLL16(gV,  S16 + nxt * 16384 + ldsVo);
      GLL16(gV2, S16 + nxt * 16384 + ldsVo + 512);
      gK += 128 * DH_; gK2 += 128 * DH_; gV += 128; gV2 += 128;
      // Counted wait: 4 newest (buf[nxt]) stay in flight; buf[cur]'s landed.
      asm volatile("s_waitcnt vmcnt(4)" ::: "memory");
      asm volatile("s_barrier" ::: "memory");
      const unsigned short* Ks = S16 + cur * 16384;
      const unsigned short* Vs = S16 + cur * 16384 + 8192;

      // Permuted K A-frags, window jw: m=c -> j-local jw*32 + 8*(c>>2)+s*4+(c&3)
      bf16x8 kf[2][2];
#pragma unroll
      for (int s = 0; s < 2; s++) {
        const int jr = jw * 32 + ((c >> 2) * 8) + s * 4 + (c & 3);
        const int swz = ((jr >> 2) & 7) ^ (jr & 3);
        kf[s][0] = *(const bf16x8*)&Ks[jr * 64 + ((quad ^ swz) * 8)];
        kf[s][1] = *(const bf16x8*)&Ks[jr * 64 + (((4 + quad) ^ swz) * 8)];
      }
      // V B-frags: B[n=d][k=jj] = V~T[d][jw*32 + quad*8 + jj]
      bf16x8 vf[4];
#pragma unroll
      for (int dt = 0; dt < 4; dt++) {
        const int d = dt * 16 + c;
        vf[dt] = *(const bf16x8*)&Vs[d * 128 + (((jw * 4 + quad) ^ (d & 15)) * 8)];
      }

      __builtin_amdgcn_s_setprio(1);
#pragma unroll
      for (int ib = 0; ib < 2; ib++) {
        f32x4 s0 = {0.f, 0.f, 0.f, 0.f}, s1 = {0.f, 0.f, 0.f, 0.f};
        s0 = MFMA32(kf[0][0], qa[ib][0], s0);
        s0 = MFMA32(kf[0][1], qa[ib][1], s0);
        s1 = MFMA32(kf[1][0], qa[ib][0], s1);
        s1 = MFMA32(kf[1][1], qa[ib][1], s1);
        i32x4 pi;
        pi[0] = pack2bf(FAST_EXP2(s0[0]), FAST_EXP2(s0[1]));
        pi[1] = pack2bf(FAST_EXP2(s0[2]), FAST_EXP2(s0[3]));
        pi[2] = pack2bf(FAST_EXP2(s1[0]), FAST_EXP2(s1[1]));
        pi[3] = pack2bf(FAST_EXP2(s1[2]), FAST_EXP2(s1[3]));
        bf16x8 pf = *(bf16x8*)&pi;
#pragma unroll
        for (int dt = 0; dt < 4; dt++)
          of[ib][dt] = MFMA32(pf, vf[dt], of[ib][dt]);
      }
      __builtin_amdgcn_s_setprio(0);
      asm volatile("s_barrier" ::: "memory");
    }
  }

  // Tree reduce over the 4 jw-waves per i-half (disjoint j). Buffers dead.
  __syncthreads();
  if (jw >= 2) {
    float* dst = Rf + (iw * 2 + (jw - 2)) * 2048;
#pragma unroll
    for (int ib = 0; ib < 2; ib++)
#pragma unroll
      for (int dt = 0; dt < 4; dt++)
        *(f32x4*)&dst[lane * 32 + (((ib * 4 + dt) ^ (lane & 7)) * 4)] = of[ib][dt];
  }
  __syncthreads();
  if (jw < 2) {
    const float* src = Rf + (iw * 2 + jw) * 2048;
#pragma unroll
    for (int ib = 0; ib < 2; ib++)
#pragma unroll
      for (int dt = 0; dt < 4; dt++)
        of[ib][dt] += *(const f32x4*)&src[lane * 32 + (((ib * 4 + dt) ^ (lane & 7)) * 4)];
  }
  __syncthreads();
  if (jw == 1) {
    float* dst = Rf + iw * 2048;
#pragma unroll
    for (int ib = 0; ib < 2; ib++)
#pragma unroll
      for (int dt = 0; dt < 4; dt++)
        *(f32x4*)&dst[lane * 32 + (((ib * 4 + dt) ^ (lane & 7)) * 4)] = of[ib][dt];
  }
  __syncthreads();
  if (jw == 0) {
    const float* src = Rf + iw * 2048;
#pragma unroll
    for (int ib = 0; ib < 2; ib++)
#pragma unroll
      for (int dt = 0; dt < 4; dt++) {
        of[ib][dt] += *(const f32x4*)&src[lane * 32 + (((ib * 4 + dt) ^ (lane & 7)) * 4)];
#pragma unroll
        for (int r = 0; r < 4; r++)
          ob16[((size_t)bb * N_ + i0 + iw * 32 + ib * 16 + quad * 4 + r) * C_ +
               hh * DH_ + dt * 16 + c] = f2bf(of[ib][dt][r]);
      }
  }
}

// ---------------------------------------------------------------------------
// Kernel 6 (MFMA): out = o @ Wo + bo  (fp32 out).
// grid (256 rowtiles of 32, 2 col-halves of 128) = 512 blocks -> 2 blocks/CU.
// ---------------------------------------------------------------------------
__global__ __launch_bounds__(256) void outproj_kernel(
    const unsigned short* __restrict__ ob16, const unsigned short* __restrict__ WoT,
    const float* __restrict__ bo, float* __restrict__ out) {
  const int rt = blockIdx.x;
  const int ch2 = blockIdx.y;
  const int t = threadIdx.x;
  const int w = t >> 6, lane = t & 63, c = lane & 15, quad = lane >> 4;
  __shared__ unsigned short As[32 * 64];    // 4 KB
  __shared__ unsigned short Bs[128 * 64];   // 16 KB

  f32x4 acc[2][2];
#pragma unroll
  for (int mt = 0; mt < 2; mt++)
#pragma unroll
    for (int nt = 0; nt < 2; nt++) acc[mt][nt] = (f32x4){0.f, 0.f, 0.f, 0.f};

  for (int kt = 0; kt < C_; kt += 64) {
    __syncthreads();
    {
      const int row = t >> 3, ch = t & 7;
      *(bf16x8*)&As[row * 64 + ((ch ^ (row & 7)) * 8)] =
          *(const bf16x8*)&ob16[((size_t)rt * 32 + row) * C_ + kt + ch * 8];
    }
#pragma unroll
    for (int p = 0; p < 4; p++) {
      const int e = t + p * 256;
      const int row = e >> 3, ch = e & 7;
      *(bf16x8*)&Bs[row * 64 + ((ch ^ (row & 7)) * 8)] =
          *(const bf16x8*)&WoT[(size_t)(ch2 * 128 + row) * C_ + kt + ch * 8];
    }
    __syncthreads();
#pragma unroll
    for (int kh = 0; kh < 2; kh++) {
      bf16x8 a[2];
#pragma unroll
      for (int mt = 0; mt < 2; mt++) {
        const int i = mt * 16 + c;
        a[mt] = *(const bf16x8*)&As[i * 64 + (((kh * 4 + quad) ^ (i & 7)) * 8)];
      }
#pragma unroll
      for (int nt = 0; nt < 2; nt++) {
        const int n = w * 32 + nt * 16 + c;
        bf16x8 b = *(const bf16x8*)&Bs[n * 64 + (((kh * 4 + quad) ^ (n & 7)) * 8)];
        acc[0][nt] = MFMA32(a[0], b, acc[0][nt]);
        acc[1][nt] = MFMA32(a[1], b, acc[1][nt]);
      }
    }
  }
#pragma unroll
  for (int mt = 0; mt < 2; mt++)
#pragma unroll
    for (int nt = 0; nt < 2; nt++) {
      const int col = ch2 * 128 + w * 32 + nt * 16 + c;
      const float bias = bo[col];
#pragma unroll
      for (int r = 0; r < 4; r++)
        out[((size_t)rt * 32 + mt * 16 + quad * 4 + r) * C_ + col] = acc[mt][nt][r] + bias;
    }
}

// ---------------------------------------------------------------------------
extern "C" void kernel_launch(void* const* d_in, const int* in_sizes, int n_in,
                              void* d_out, int out_size, void* d_ws, size_t ws_size,
                              hipStream_t stream) {
  const float* x    = (const float*)d_in[0];
  const float* pos  = (const float*)d_in[1];
  const float* Wq   = (const float*)d_in[2];
  const float* bq   = (const float*)d_in[3];
  const float* Wk   = (const float*)d_in[4];
  const float* bk   = (const float*)d_in[5];
  const float* Wv   = (const float*)d_in[6];
  const float* bv   = (const float*)d_in[7];
  const float* Wo   = (const float*)d_in[8];
  const float* bo   = (const float*)d_in[9];
  const float* ln_g = (const float*)d_in[10];
  const float* ln_b = (const float*)d_in[11];
  float* out = (float*)d_out;

  // Workspace (u16): h16|q16|k16|vT16|ob16 (2M each) | W3T 196608 | WoT 65536
  const size_t SZ = (size_t)B_ * N_ * C_;   // 2097152
  unsigned short* h16  = (unsigned short*)d_ws;
  unsigned short* q16  = h16 + SZ;
  unsigned short* k16  = q16 + SZ;
  unsigned short* vT16 = k16 + SZ;
  unsigned short* ob16 = vT16 + SZ;
  unsigned short* W3T  = ob16 + SZ;
  unsigned short* WoT  = W3T + (size_t)H_ * 192 * 256;

  ln_kernel<<<B_ * N_ / 4, 256, 0, stream>>>(x, pos, ln_g, ln_b, h16);
  wconv_kernel<<<128, 256, 0, stream>>>(Wq, Wk, Wv, Wo, W3T, WoT);
  qkv_kernel<<<dim3(128, H_), 256, 0, stream>>>(h16, W3T, bq, bk, bv, q16, k16, vT16);
  colstats_kernel<<<512, 512, 0, stream>>>(q16, k16, vT16);
  attnout_kernel<<<512, 512, 0, stream>>>(q16, k16, vT16, ob16);
  outproj_kernel<<<dim3(256, 2), 256, 0, stream>>>(ob16, WoT, bo, out);
}

// Round 4
// 177.374 us; speedup vs baseline: 2.7859x; 2.7859x over previous
//
#include <hip/hip_runtime.h>
#include <math.h>

// Problem constants
#define B_ 2
#define N_ 4096
#define C_ 256
#define H_ 4
#define DH_ 64
#define EPS_ 1e-6f
// 1/sqrt(DH) * log2(e), folded into Wq/bq so P = exp2(s) directly
#define SCALE_Q_ 0.18033688011112042f

typedef short bf16x8 __attribute__((ext_vector_type(8)));   // 8 bf16 in 4 VGPRs
typedef short bf16x4v __attribute__((ext_vector_type(4)));  // 4 bf16 in 2 VGPRs
typedef float f32x4 __attribute__((ext_vector_type(4)));
typedef int i32x4 __attribute__((ext_vector_type(4)));

// Only HW-verified gfx950 builtins, called directly — NO __has_builtin (host
// pass returns false for target builtins) and NO inline-asm trans ops (R6).
// REGISTER RULE (R8, R11, re-confirmed the hard way in R17): at
// launch_bounds(512,4) the arch-VGPR cap is 64 — exceeding it spills to
// scratch and the kernel drowns in HBM traffic (R17: colstats 362us,
// FETCH 714MB = spill reloads). Anything needing >64 arch VGPRs uses
// 256 threads with launch_bounds(256,2) or default.
// PREFETCH RULE (R16): plain C++ register prefetch gets SUNK by the
// compiler to the consume point (R2: colstats VGPR=36 proved it) — software
// pipelining must use side-effecting ops (global_load_lds) the compiler
// cannot reorder/sink.
#define MFMA32(a, b, c) __builtin_amdgcn_mfma_f32_16x16x32_bf16(a, b, c, 0, 0, 0)
#define FAST_EXP2(x) __builtin_amdgcn_exp2f(x)   // v_exp_f32, hazard-aware

// Direct global->LDS (16B/lane). LDS dest is wave-uniform base + lane*16
// (m104): dest must be LINEAR in lane order; swizzle is applied by
// pre-swizzling the per-lane GLOBAL source address (m173 / rule #21).
typedef const unsigned int __attribute__((address_space(1)))* gptr_as1;
typedef unsigned int __attribute__((address_space(3)))* lptr_as3;
#define GLL16(gp, lp)                                                   \
  __builtin_amdgcn_global_load_lds(                                     \
      (gptr_as1)(unsigned long long)(const void*)(gp),                  \
      (lptr_as3)(unsigned int)(unsigned long long)(const void*)(lp),    \
      16, 0, 0)

__device__ __forceinline__ unsigned short f2bf(float x) {
  unsigned int u = __float_as_uint(x);
  return (unsigned short)((u + 0x7FFFu + ((u >> 16) & 1u)) >> 16);  // RNE
}
__device__ __forceinline__ float bf2f(unsigned short u) {
  return __uint_as_float(((unsigned int)u) << 16);
}
// Pack two floats to two bf16 (round-half-up) in one v_perm_b32.
__device__ __forceinline__ int pack2bf(float lo, float hi) {
  return (int)__builtin_amdgcn_perm(__float_as_uint(hi) + 0x8000u,
                                    __float_as_uint(lo) + 0x8000u, 0x07060302u);
}

// ---------------------------------------------------------------------------
// Kernel 1: h16 = bf16(LayerNorm(x + pos) * g + b)
// Wave-per-row: float4 loads, pure shuffle reduce, no LDS/barriers. grid 2048.
// ---------------------------------------------------------------------------
__global__ __launch_bounds__(256) void ln_kernel(
    const float* __restrict__ x, const float* __restrict__ pos,
    const float* __restrict__ g, const float* __restrict__ beta,
    unsigned short* __restrict__ h16) {
  const int w = threadIdx.x >> 6, lane = threadIdx.x & 63;
  const int row = blockIdx.x * 4 + w;
  const float4 xv = *(const float4*)&x[row * C_ + lane * 4];
  const float4 pv = *(const float4*)&pos[row * C_ + lane * 4];
  float4 v = {xv.x + pv.x, xv.y + pv.y, xv.z + pv.z, xv.w + pv.w};
  float s = v.x + v.y + v.z + v.w;
  s += __shfl_xor(s, 1);  s += __shfl_xor(s, 2);  s += __shfl_xor(s, 4);
  s += __shfl_xor(s, 8);  s += __shfl_xor(s, 16); s += __shfl_xor(s, 32);
  const float mu = s * (1.0f / C_);
  float4 d = {v.x - mu, v.y - mu, v.z - mu, v.w - mu};
  float q = d.x * d.x + d.y * d.y + d.z * d.z + d.w * d.w;
  q += __shfl_xor(q, 1);  q += __shfl_xor(q, 2);  q += __shfl_xor(q, 4);
  q += __shfl_xor(q, 8);  q += __shfl_xor(q, 16); q += __shfl_xor(q, 32);
  const float rs = rsqrtf(q * (1.0f / C_) + EPS_);
  const float4 g4 = *(const float4*)&g[lane * 4];
  const float4 b4 = *(const float4*)&beta[lane * 4];
  bf16x4v o;
  o[0] = (short)f2bf(d.x * rs * g4.x + b4.x);
  o[1] = (short)f2bf(d.y * rs * g4.y + b4.y);
  o[2] = (short)f2bf(d.z * rs * g4.z + b4.z);
  o[3] = (short)f2bf(d.w * rs * g4.w + b4.w);
  *(bf16x4v*)&h16[row * C_ + lane * 4] = o;
}

// ---------------------------------------------------------------------------
// Kernel 2: weight transpose+cast to bf16 B-frag layout [n][k].
// ---------------------------------------------------------------------------
__global__ __launch_bounds__(256) void wconv_kernel(
    const float* __restrict__ Wq, const float* __restrict__ Wk,
    const float* __restrict__ Wv, const float* __restrict__ Wo,
    unsigned short* __restrict__ W3T, unsigned short* __restrict__ WoT) {
  const int base = blockIdx.x * 2048;
#pragma unroll
  for (int p = 0; p < 8; p++) {
    const int idx = base + p * 256 + threadIdx.x;
    if (idx < 196608) {
      const int m = idx >> 14;           // 0..11
      const int rem = idx & 16383;
      const int c = rem >> 6, d = rem & 63;
      const int h = m / 3, kind = m - h * 3;
      const float* W = kind == 0 ? Wq : kind == 1 ? Wk : Wv;
      float v = W[h * 16384 + rem];
      if (kind == 0) v *= SCALE_Q_;
      W3T[(h * 192 + kind * 64 + d) * 256 + c] = f2bf(v);
    } else {
      const int widx = idx - 196608;     // < 65536
      const int k = widx >> 8, n = widx & 255;
      WoT[n * 256 + k] = f2bf(Wo[widx]);
    }
  }
}

// ---------------------------------------------------------------------------
// Kernel 3 (MFMA): q/k/v projections.  q16,k16: [bh][n][64]; vT16: [bh][64][N]
// 64-row tiles, grid (128, H) = 512 blocks (2/CU). Wave w owns 16 rows.
// ---------------------------------------------------------------------------
__global__ __launch_bounds__(256) void qkv_kernel(
    const unsigned short* __restrict__ h16, const unsigned short* __restrict__ W3T,
    const float* __restrict__ bq, const float* __restrict__ bk,
    const float* __restrict__ bv,
    unsigned short* __restrict__ q16, unsigned short* __restrict__ k16,
    unsigned short* __restrict__ vT16) {
  const int rt = blockIdx.x;
  const int hh = blockIdx.y;
  const int t = threadIdx.x;
  const int w = t >> 6, lane = t & 63, c = lane & 15, quad = lane >> 4;
  __shared__ unsigned short Hs[64 * 64];    // 8 KB
  __shared__ unsigned short Bs[192 * 64];   // 24 KB
  const int row0 = rt * 64;

  f32x4 acc[12];
#pragma unroll
  for (int nt = 0; nt < 12; nt++) acc[nt] = (f32x4){0.f, 0.f, 0.f, 0.f};

  for (int kt = 0; kt < C_; kt += 64) {
    __syncthreads();
#pragma unroll
    for (int p = 0; p < 2; p++) {
      const int e = t + p * 256;
      const int row = e >> 3, ch = e & 7;
      *(bf16x8*)&Hs[row * 64 + ((ch ^ (row & 7)) * 8)] =
          *(const bf16x8*)&h16[(size_t)(row0 + row) * C_ + kt + ch * 8];
    }
#pragma unroll
    for (int p = 0; p < 6; p++) {
      const int e = t + p * 256;
      const int row = e >> 3, ch = e & 7;
      *(bf16x8*)&Bs[row * 64 + ((ch ^ (row & 7)) * 8)] =
          *(const bf16x8*)&W3T[(size_t)(hh * 192 + row) * C_ + kt + ch * 8];
    }
    __syncthreads();
#pragma unroll
    for (int kh = 0; kh < 2; kh++) {
      const int i = w * 16 + c;
      bf16x8 a = *(const bf16x8*)&Hs[i * 64 + (((kh * 4 + quad) ^ (i & 7)) * 8)];
#pragma unroll
      for (int nt = 0; nt < 12; nt++) {
        const int n = nt * 16 + c;
        bf16x8 b = *(const bf16x8*)&Bs[n * 64 + (((kh * 4 + quad) ^ (n & 7)) * 8)];
        acc[nt] = MFMA32(a, b, acc[nt]);
      }
    }
  }
#pragma unroll
  for (int nt = 0; nt < 12; nt++) {
    const int kind = nt >> 2;
    const int col = (nt & 3) * 16 + c;
    const float bias = kind == 0 ? bq[hh * 64 + col] * SCALE_Q_
                     : kind == 1 ? bk[hh * 64 + col] : bv[hh * 64 + col];
#pragma unroll
    for (int r = 0; r < 4; r++) {
      const int gr = row0 + w * 16 + quad * 4 + r;
      const int b = gr >> 12, n = gr & (N_ - 1);
      const size_t bh = (size_t)(b * H_ + hh);
      const unsigned short val = f2bf(acc[nt][r] + bias);
      if (kind == 0)      q16[(bh * N_ + n) * DH_ + col] = val;
      else if (kind == 1) k16[(bh * N_ + n) * DH_ + col] = val;
      else                vT16[(bh * DH_ + col) * N_ + n] = val;
    }
  }
}

// ---------------------------------------------------------------------------
// Kernel 4 (MFMA): l_j = sum_i exp2(s~_ij); vT16 *= 1/l in place.
// R18: R16's design at the RIGHT register budget.
//   - R17 failure: launch_bounds(512,4) caps arch VGPR at 64; ka[4][2]+lsum
//     needs ~80 -> scratch spill -> 1.2GB HBM traffic, 362us. Fix: 256 thr,
//     launch_bounds(256,2) (cap ~256, actual ~90-110, no spill).
//   - gll staging kept: side-effecting, compiler can't sink (R16).
//   - Wave-private LDS bufs -> ZERO barriers in main loop.
//   - Ring-of-4 buffers, depth-2 prefetch, vmcnt(4): only 8 waves/CU are
//     resident (grid 512 x 4 waves), so pipeline depth covers L2 latency.
//   - 64 j/block: Q L2 traffic 256MB (~7.4us floor); trans floor ~7us.
// grid 512 (bh = blk&7, 64 j-cols) x 256 thr. Wave w stages/consumes its own
// 16 i-rows per round; 4 waves cover 64 i; 64 rounds.
// ---------------------------------------------------------------------------
__global__ __launch_bounds__(256, 2) void colstats_kernel(
    const unsigned short* __restrict__ q16, const unsigned short* __restrict__ k16,
    unsigned short* __restrict__ vT16) {
  const int blk = blockIdx.x;
  const int bh = blk & 7;
  const int j0 = (blk >> 3) * 64;
  const int t = threadIdx.x;
  const int w = t >> 6, lane = t & 63, c = lane & 15, quad = lane >> 4;
  // Ring of 4 wave-private Q bufs: buf p at p*4096 u16, wave w at +w*1024.
  // Each seg: 16 rows x 64 d, swizzle slot = ch ^ (row&7).
  __shared__ __align__(16) unsigned short Qb[4 * 4 * 1024];   // 32 KB
  __shared__ float Lp[4][64];
  __shared__ float ilv[64];

  // K A-frags for 64 j: rows j0 + jb*16 + c, k-halves 0/32.  32 VGPRs.
  bf16x8 ka[4][2];
#pragma unroll
  for (int jb = 0; jb < 4; jb++) {
    const size_t kb = ((size_t)bh * N_ + j0 + jb * 16 + c) * DH_;
    ka[jb][0] = *(const bf16x8*)&k16[kb + quad * 8];
    ka[jb][1] = *(const bf16x8*)&k16[kb + 32 + quad * 8];
  }

  // Pre-swizzled gll source: lane l -> row_l = l>>3 (0..7), slot = l&7,
  // content chunk ch = slot ^ row_l ((w*16+rl)&7 == rl, (8+rl)&7 == rl).
  const int rl = lane >> 3, sl = lane & 7;
  const unsigned short* gQ =
      q16 + ((size_t)bh * N_ + w * 16 + rl) * DH_ + ((sl ^ rl) * 8);
  const int woff = w * 1024;           // wave's u16 offset within a buffer

  f32x4 lsum[4];
#pragma unroll
  for (int jb = 0; jb < 4; jb++) lsum[jb] = (f32x4){0.f, 0.f, 0.f, 0.f};

  // Prologue: stage rounds 0,1 into bufs 0,1 (4 glls in flight).
  GLL16(gQ, Qb + woff);  GLL16(gQ + 512, Qb + woff + 512);
  gQ += 64 * DH_;
  GLL16(gQ, Qb + 4096 + woff);  GLL16(gQ + 4096 /*dummy-align*/ - 4096 + 512, Qb + 4096 + woff + 512);
  gQ += 64 * DH_;

  for (int r4 = 0; r4 < 64; r4 += 4) {
#pragma unroll
    for (int hf = 0; hf < 4; hf++) {     // literal buf indices after unroll
      const int cur = hf, pre = (hf + 2) & 3;
      // Prefetch round r+2 into buf[pre] (free since round r-2).
      // Final rounds over-read adjacent allocated workspace — never consumed.
      GLL16(gQ, Qb + pre * 4096 + woff);
      GLL16(gQ + 512, Qb + pre * 4096 + woff + 512);
      gQ += 64 * DH_;
      // Wave-private: wait own 2 oldest (round r landed); 4 newer in flight.
      asm volatile("s_waitcnt vmcnt(4)" ::: "memory");
      const unsigned short* Qs = Qb + cur * 4096 + woff;
      bf16x8 qf0 = *(const bf16x8*)&Qs[c * 64 + ((quad ^ (c & 7)) * 8)];
      bf16x8 qf1 = *(const bf16x8*)&Qs[c * 64 + (((4 + quad) ^ (c & 7)) * 8)];
#pragma unroll
      for (int jb = 0; jb < 4; jb++) {
        f32x4 s = {0.f, 0.f, 0.f, 0.f};
        s = MFMA32(ka[jb][0], qf0, s);
        s = MFMA32(ka[jb][1], qf1, s);
#pragma unroll
        for (int r = 0; r < 4; r++) lsum[jb][r] += FAST_EXP2(s[r]);
      }
    }
  }
  // Reduce over the 16 c-lanes (i-rows), then over 4 waves via LDS.
#pragma unroll
  for (int jb = 0; jb < 4; jb++) {
#pragma unroll
    for (int r = 0; r < 4; r++) {
      float s = lsum[jb][r];
      s += __shfl_xor(s, 1); s += __shfl_xor(s, 2);
      s += __shfl_xor(s, 4); s += __shfl_xor(s, 8);
      if (c == 0) Lp[w][jb * 16 + quad * 4 + r] = s;
    }
  }
  __syncthreads();   // full drain: also retires the tail in-flight glls
  if (t < 64)
    ilv[t] = 1.0f / (Lp[0][t] + Lp[1][t] + Lp[2][t] + Lp[3][t]);
  __syncthreads();
  // Scale this block's private 64-col vT16 slice in place: V~ = invl_j * V
  {
    const int d = t >> 2, chb = t & 3;
#pragma unroll
    for (int cc = 0; cc < 2; cc++) {
      const int ch = chb + cc * 4;
      const size_t addr = ((size_t)bh * DH_ + d) * N_ + j0 + ch * 8;
      bf16x8 v = *(const bf16x8*)&vT16[addr];
#pragma unroll
      for (int jj = 0; jj < 8; jj++)
        v[jj] = (short)f2bf(bf2f((unsigned short)v[jj]) * ilv[ch * 8 + jj]);
      *(bf16x8*)&vT16[addr] = v;
    }
  }
}

// ---------------------------------------------------------------------------
// Kernel 5 (MFMA): O[i,d] = sum_j exp2(s~_ij) * V~[j,d]
// R14 staging (gll double-buffer, counted vmcnt(4), raw barriers, setprio) +
// R15 x2 unroll (literal LDS bases). Proven 43.5us.
// grid 512 x 512 thr (8 waves), launch_bounds(512,4) -> 16 waves/CU.
// ---------------------------------------------------------------------------
__global__ __launch_bounds__(512, 4) void attnout_kernel(
    const unsigned short* __restrict__ q16, const unsigned short* __restrict__ k16,
    const unsigned short* __restrict__ vT16, unsigned short* __restrict__ ob16) {
  const int blk = blockIdx.x;
  const int bh = blk & 7;
  const int bb = bh >> 2, hh = bh & 3;
  const int i0 = (blk >> 3) * 64;
  const int t = threadIdx.x;
  const int w = t >> 6, lane = t & 63, c = lane & 15, quad = lane >> 4;
  const int iw = w >> 2;           // 0..1: 32-i half
  const int jw = w & 3;            // 0..3: 32-j window of the 128-j stage

  // Double buffer: buf b at u16 offset b*16384: Ks [128 j][64 d] | Vs [64 d][128 j]
  __shared__ __align__(16) char smem[65536];
  unsigned short* S16 = (unsigned short*)smem;
  float* Rf = (float*)smem;        // epilogue reduce: 4 x 8KB regions

  // Q B-frags: rows i = i0 + iw*32 + ib*16 + c
  bf16x8 qa[2][2];
#pragma unroll
  for (int ib = 0; ib < 2; ib++) {
    const size_t qb = ((size_t)bh * N_ + i0 + iw * 32 + ib * 16 + c) * DH_;
    qa[ib][0] = *(const bf16x8*)&q16[qb + quad * 8];
    qa[ib][1] = *(const bf16x8*)&q16[qb + 32 + quad * 8];
  }

  // Pre-swizzled gll source addresses (rule #21: linear LDS dest, inverse-
  // swizzled global source, swizzled read).
  const int krow  = w * 16 + (lane >> 3);
  const int kch   = (lane & 7) ^ (((krow >> 2) & 7) ^ (krow & 3));
  const int krow2 = krow + 8;
  const int kch2  = (lane & 7) ^ (((krow2 >> 2) & 7) ^ (krow2 & 3));
  const unsigned short* gK  = k16 + ((size_t)bh * N_ + krow ) * DH_ + kch  * 8;
  const unsigned short* gK2 = k16 + ((size_t)bh * N_ + krow2) * DH_ + kch2 * 8;
  const int vd   = w * 8 + (lane >> 4);
  const int vch  = (lane & 15) ^ (vd & 15);
  const int vd2  = vd + 4;
  const int vch2 = (lane & 15) ^ (vd2 & 15);
  const unsigned short* gV  = vT16 + ((size_t)bh * DH_ + vd ) * N_ + vch  * 8;
  const unsigned short* gV2 = vT16 + ((size_t)bh * DH_ + vd2) * N_ + vch2 * 8;
  const int ldsKo = w * 1024;          // u16 offset of wave's K seg in buffer
  const int ldsVo = 8192 + w * 1024;   // u16 offset of wave's V seg in buffer

  f32x4 of[2][4];
#pragma unroll
  for (int ib = 0; ib < 2; ib++)
#pragma unroll
    for (int dt = 0; dt < 4; dt++) of[ib][dt] = (f32x4){0.f, 0.f, 0.f, 0.f};

  // Prologue: stage tile 0 into buf0 (4 glls -> vmcnt outstanding = 4).
  GLL16(gK,  S16 + ldsKo);       GLL16(gK2, S16 + ldsKo + 512);
  GLL16(gV,  S16 + ldsVo);       GLL16(gV2, S16 + ldsVo + 512);
  gK += 128 * DH_; gK2 += 128 * DH_; gV += 128; gV2 += 128;

  for (int jt = 0; jt < N_; jt += 256) {
#pragma unroll
    for (int half = 0; half < 2; half++) {   // half -> literal cur after unroll
      const int cur = half, nxt = half ^ 1;
      GLL16(gK,  S16 + nxt * 16384 + ldsKo);
      GLL16(gK2, S16 + nxt * 16384 + ldsKo + 512);
      GLL16(gV,  S16 + nxt * 16384 + ldsVo);
      GLL16(gV2, S16 + nxt * 16384 + ldsVo + 512);
      gK += 128 * DH_; gK2 += 128 * DH_; gV += 128; gV2 += 128;
      // Counted wait: 4 newest (buf[nxt]) stay in flight; buf[cur]'s landed.
      asm volatile("s_waitcnt vmcnt(4)" ::: "memory");
      asm volatile("s_barrier" ::: "memory");
      const unsigned short* Ks = S16 + cur * 16384;
      const unsigned short* Vs = S16 + cur * 16384 + 8192;

      // Permuted K A-frags, window jw: m=c -> j-local jw*32 + 8*(c>>2)+s*4+(c&3)
      bf16x8 kf[2][2];
#pragma unroll
      for (int s = 0; s < 2; s++) {
        const int jr = jw * 32 + ((c >> 2) * 8) + s * 4 + (c & 3);
        const int swz = ((jr >> 2) & 7) ^ (jr & 3);
        kf[s][0] = *(const bf16x8*)&Ks[jr * 64 + ((quad ^ swz) * 8)];
        kf[s][1] = *(const bf16x8*)&Ks[jr * 64 + (((4 + quad) ^ swz) * 8)];
      }
      // V B-frags: B[n=d][k=jj] = V~T[d][jw*32 + quad*8 + jj]
      bf16x8 vf[4];
#pragma unroll
      for (int dt = 0; dt < 4; dt++) {
        const int d = dt * 16 + c;
        vf[dt] = *(const bf16x8*)&Vs[d * 128 + (((jw * 4 + quad) ^ (d & 15)) * 8)];
      }

      __builtin_amdgcn_s_setprio(1);
#pragma unroll
      for (int ib = 0; ib < 2; ib++) {
        f32x4 s0 = {0.f, 0.f, 0.f, 0.f}, s1 = {0.f, 0.f, 0.f, 0.f};
        s0 = MFMA32(kf[0][0], qa[ib][0], s0);
        s0 = MFMA32(kf[0][1], qa[ib][1], s0);
        s1 = MFMA32(kf[1][0], qa[ib][0], s1);
        s1 = MFMA32(kf[1][1], qa[ib][1], s1);
        i32x4 pi;
        pi[0] = pack2bf(FAST_EXP2(s0[0]), FAST_EXP2(s0[1]));
        pi[1] = pack2bf(FAST_EXP2(s0[2]), FAST_EXP2(s0[3]));
        pi[2] = pack2bf(FAST_EXP2(s1[0]), FAST_EXP2(s1[1]));
        pi[3] = pack2bf(FAST_EXP2(s1[2]), FAST_EXP2(s1[3]));
        bf16x8 pf = *(bf16x8*)&pi;
#pragma unroll
        for (int dt = 0; dt < 4; dt++)
          of[ib][dt] = MFMA32(pf, vf[dt], of[ib][dt]);
      }
      __builtin_amdgcn_s_setprio(0);
      asm volatile("s_barrier" ::: "memory");
    }
  }

  // Tree reduce over the 4 jw-waves per i-half (disjoint j). Buffers dead.
  __syncthreads();
  if (jw >= 2) {
    float* dst = Rf + (iw * 2 + (jw - 2)) * 2048;
#pragma unroll
    for (int ib = 0; ib < 2; ib++)
#pragma unroll
      for (int dt = 0; dt < 4; dt++)
        *(f32x4*)&dst[lane * 32 + (((ib * 4 + dt) ^ (lane & 7)) * 4)] = of[ib][dt];
  }
  __syncthreads();
  if (jw < 2) {
    const float* src = Rf + (iw * 2 + jw) * 2048;
#pragma unroll
    for (int ib = 0; ib < 2; ib++)
#pragma unroll
      for (int dt = 0; dt < 4; dt++)
        of[ib][dt] += *(const f32x4*)&src[lane * 32 + (((ib * 4 + dt) ^ (lane & 7)) * 4)];
  }
  __syncthreads();
  if (jw == 1) {
    float* dst = Rf + iw * 2048;
#pragma unroll
    for (int ib = 0; ib < 2; ib++)
#pragma unroll
      for (int dt = 0; dt < 4; dt++)
        *(f32x4*)&dst[lane * 32 + (((ib * 4 + dt) ^ (lane & 7)) * 4)] = of[ib][dt];
  }
  __syncthreads();
  if (jw == 0) {
    const float* src = Rf + iw * 2048;
#pragma unroll
    for (int ib = 0; ib < 2; ib++)
#pragma unroll
      for (int dt = 0; dt < 4; dt++) {
        of[ib][dt] += *(const f32x4*)&src[lane * 32 + (((ib * 4 + dt) ^ (lane & 7)) * 4)];
#pragma unroll
        for (int r = 0; r < 4; r++)
          ob16[((size_t)bb * N_ + i0 + iw * 32 + ib * 16 + quad * 4 + r) * C_ +
               hh * DH_ + dt * 16 + c] = f2bf(of[ib][dt][r]);
      }
  }
}

// ---------------------------------------------------------------------------
// Kernel 6 (MFMA): out = o @ Wo + bo  (fp32 out).
// grid (256 rowtiles of 32, 2 col-halves of 128) = 512 blocks -> 2 blocks/CU.
// ---------------------------------------------------------------------------
__global__ __launch_bounds__(256) void outproj_kernel(
    const unsigned short* __restrict__ ob16, const unsigned short* __restrict__ WoT,
    const float* __restrict__ bo, float* __restrict__ out) {
  const int rt = blockIdx.x;
  const int ch2 = blockIdx.y;
  const int t = threadIdx.x;
  const int w = t >> 6, lane = t & 63, c = lane & 15, quad = lane >> 4;
  __shared__ unsigned short As[32 * 64];    // 4 KB
  __shared__ unsigned short Bs[128 * 64];   // 16 KB

  f32x4 acc[2][2];
#pragma unroll
  for (int mt = 0; mt < 2; mt++)
#pragma unroll
    for (int nt = 0; nt < 2; nt++) acc[mt][nt] = (f32x4){0.f, 0.f, 0.f, 0.f};

  for (int kt = 0; kt < C_; kt += 64) {
    __syncthreads();
    {
      const int row = t >> 3, ch = t & 7;
      *(bf16x8*)&As[row * 64 + ((ch ^ (row & 7)) * 8)] =
          *(const bf16x8*)&ob16[((size_t)rt * 32 + row) * C_ + kt + ch * 8];
    }
#pragma unroll
    for (int p = 0; p < 4; p++) {
      const int e = t + p * 256;
      const int row = e >> 3, ch = e & 7;
      *(bf16x8*)&Bs[row * 64 + ((ch ^ (row & 7)) * 8)] =
          *(const bf16x8*)&WoT[(size_t)(ch2 * 128 + row) * C_ + kt + ch * 8];
    }
    __syncthreads();
#pragma unroll
    for (int kh = 0; kh < 2; kh++) {
      bf16x8 a[2];
#pragma unroll
      for (int mt = 0; mt < 2; mt++) {
        const int i = mt * 16 + c;
        a[mt] = *(const bf16x8*)&As[i * 64 + (((kh * 4 + quad) ^ (i & 7)) * 8)];
      }
#pragma unroll
      for (int nt = 0; nt < 2; nt++) {
        const int n = w * 32 + nt * 16 + c;
        bf16x8 b = *(const bf16x8*)&Bs[n * 64 + (((kh * 4 + quad) ^ (n & 7)) * 8)];
        acc[0][nt] = MFMA32(a[0], b, acc[0][nt]);
        acc[1][nt] = MFMA32(a[1], b, acc[1][nt]);
      }
    }
  }
#pragma unroll
  for (int mt = 0; mt < 2; mt++)
#pragma unroll
    for (int nt = 0; nt < 2; nt++) {
      const int col = ch2 * 128 + w * 32 + nt * 16 + c;
      const float bias = bo[col];
#pragma unroll
      for (int r = 0; r < 4; r++)
        out[((size_t)rt * 32 + mt * 16 + quad * 4 + r) * C_ + col] = acc[mt][nt][r] + bias;
    }
}

// ---------------------------------------------------------------------------
extern "C" void kernel_launch(void* const* d_in, const int* in_sizes, int n_in,
                              void* d_out, int out_size, void* d_ws, size_t ws_size,
                              hipStream_t stream) {
  const float* x    = (const float*)d_in[0];
  const float* pos  = (const float*)d_in[1];
  const float* Wq   = (const float*)d_in[2];
  const float* bq   = (const float*)d_in[3];
  const float* Wk   = (const float*)d_in[4];
  const float* bk   = (const float*)d_in[5];
  const float* Wv   = (const float*)d_in[6];
  const float* bv   = (const float*)d_in[7];
  const float* Wo   = (const float*)d_in[8];
  const float* bo   = (const float*)d_in[9];
  const float* ln_g = (const float*)d_in[10];
  const float* ln_b = (const float*)d_in[11];
  float* out = (float*)d_out;

  // Workspace (u16): h16|q16|k16|vT16|ob16 (2M each) | W3T 196608 | WoT 65536
  const size_t SZ = (size_t)B_ * N_ * C_;   // 2097152
  unsigned short* h16  = (unsigned short*)d_ws;
  unsigned short* q16  = h16 + SZ;
  unsigned short* k16  = q16 + SZ;
  unsigned short* vT16 = k16 + SZ;
  unsigned short* ob16 = vT16 + SZ;
  unsigned short* W3T  = ob16 + SZ;
  unsigned short* WoT  = W3T + (size_t)H_ * 192 * 256;

  ln_kernel<<<B_ * N_ / 4, 256, 0, stream>>>(x, pos, ln_g, ln_b, h16);
  wconv_kernel<<<128, 256, 0, stream>>>(Wq, Wk, Wv, Wo, W3T, WoT);
  qkv_kernel<<<dim3(128, H_), 256, 0, stream>>>(h16, W3T, bq, bk, bv, q16, k16, vT16);
  colstats_kernel<<<512, 256, 0, stream>>>(q16, k16, vT16);
  attnout_kernel<<<512, 512, 0, stream>>>(q16, k16, vT16, ob16);
  outproj_kernel<<<dim3(256, 2), 256, 0, stream>>>(ob16, WoT, bo, out);
}

// Round 5
// 171.205 us; speedup vs baseline: 2.8863x; 1.0360x over previous
//
#include <hip/hip_runtime.h>
#include <math.h>

// Problem constants
#define B_ 2
#define N_ 4096
#define C_ 256
#define H_ 4
#define DH_ 64
#define EPS_ 1e-6f
// 1/sqrt(DH) * log2(e), folded into Wq/bq so P = exp2(s) directly
#define SCALE_Q_ 0.18033688011112042f

typedef short bf16x8 __attribute__((ext_vector_type(8)));   // 8 bf16 in 4 VGPRs
typedef short bf16x4v __attribute__((ext_vector_type(4)));  // 4 bf16 in 2 VGPRs
typedef float f32x4 __attribute__((ext_vector_type(4)));
typedef int i32x4 __attribute__((ext_vector_type(4)));

// Only HW-verified gfx950 builtins, called directly — NO __has_builtin (host
// pass returns false for target builtins) and NO inline-asm trans ops (R6).
// REGISTER RULE (R8, R11, re-confirmed in R17): at launch_bounds(512,4) the
// arch-VGPR cap is 64 — exceeding it spills to scratch and drowns in HBM
// traffic (R17: colstats 362us, FETCH 714MB = spill reloads). Anything
// needing >64 arch VGPRs uses 256 threads with launch_bounds(256,2).
// PREFETCH RULE (R16): plain C++ register prefetch gets SUNK by the
// compiler to the consume point (R2: colstats VGPR=36 proved it) — software
// pipelining must use side-effecting ops (global_load_lds) the compiler
// cannot reorder/sink.
// LATENCY RULE (R18->R19): at 8 waves/CU, per-round work must exceed the
// L2 round-trip (~250cyc) or the pipeline stalls every round — double
// per-round ILP before adding pipeline depth.
#define MFMA32(a, b, c) __builtin_amdgcn_mfma_f32_16x16x32_bf16(a, b, c, 0, 0, 0)
#define FAST_EXP2(x) __builtin_amdgcn_exp2f(x)   // v_exp_f32, hazard-aware

// Direct global->LDS (16B/lane). LDS dest is wave-uniform base + lane*16
// (m104): dest must be LINEAR in lane order; swizzle is applied by
// pre-swizzling the per-lane GLOBAL source address (m173 / rule #21).
typedef const unsigned int __attribute__((address_space(1)))* gptr_as1;
typedef unsigned int __attribute__((address_space(3)))* lptr_as3;
#define GLL16(gp, lp)                                                   \
  __builtin_amdgcn_global_load_lds(                                     \
      (gptr_as1)(unsigned long long)(const void*)(gp),                  \
      (lptr_as3)(unsigned int)(unsigned long long)(const void*)(lp),    \
      16, 0, 0)

__device__ __forceinline__ unsigned short f2bf(float x) {
  unsigned int u = __float_as_uint(x);
  return (unsigned short)((u + 0x7FFFu + ((u >> 16) & 1u)) >> 16);  // RNE
}
__device__ __forceinline__ float bf2f(unsigned short u) {
  return __uint_as_float(((unsigned int)u) << 16);
}
// Pack two floats to two bf16 (round-half-up) in one v_perm_b32.
__device__ __forceinline__ int pack2bf(float lo, float hi) {
  return (int)__builtin_amdgcn_perm(__float_as_uint(hi) + 0x8000u,
                                    __float_as_uint(lo) + 0x8000u, 0x07060302u);
}

// ---------------------------------------------------------------------------
// Kernel 1: h16 = bf16(LayerNorm(x + pos) * g + b)
// Wave-per-row: float4 loads, pure shuffle reduce, no LDS/barriers. grid 2048.
// ---------------------------------------------------------------------------
__global__ __launch_bounds__(256) void ln_kernel(
    const float* __restrict__ x, const float* __restrict__ pos,
    const float* __restrict__ g, const float* __restrict__ beta,
    unsigned short* __restrict__ h16) {
  const int w = threadIdx.x >> 6, lane = threadIdx.x & 63;
  const int row = blockIdx.x * 4 + w;
  const float4 xv = *(const float4*)&x[row * C_ + lane * 4];
  const float4 pv = *(const float4*)&pos[row * C_ + lane * 4];
  float4 v = {xv.x + pv.x, xv.y + pv.y, xv.z + pv.z, xv.w + pv.w};
  float s = v.x + v.y + v.z + v.w;
  s += __shfl_xor(s, 1);  s += __shfl_xor(s, 2);  s += __shfl_xor(s, 4);
  s += __shfl_xor(s, 8);  s += __shfl_xor(s, 16); s += __shfl_xor(s, 32);
  const float mu = s * (1.0f / C_);
  float4 d = {v.x - mu, v.y - mu, v.z - mu, v.w - mu};
  float q = d.x * d.x + d.y * d.y + d.z * d.z + d.w * d.w;
  q += __shfl_xor(q, 1);  q += __shfl_xor(q, 2);  q += __shfl_xor(q, 4);
  q += __shfl_xor(q, 8);  q += __shfl_xor(q, 16); q += __shfl_xor(q, 32);
  const float rs = rsqrtf(q * (1.0f / C_) + EPS_);
  const float4 g4 = *(const float4*)&g[lane * 4];
  const float4 b4 = *(const float4*)&beta[lane * 4];
  bf16x4v o;
  o[0] = (short)f2bf(d.x * rs * g4.x + b4.x);
  o[1] = (short)f2bf(d.y * rs * g4.y + b4.y);
  o[2] = (short)f2bf(d.z * rs * g4.z + b4.z);
  o[3] = (short)f2bf(d.w * rs * g4.w + b4.w);
  *(bf16x4v*)&h16[row * C_ + lane * 4] = o;
}

// ---------------------------------------------------------------------------
// Kernel 2: weight transpose+cast to bf16 B-frag layout [n][k].
// ---------------------------------------------------------------------------
__global__ __launch_bounds__(256) void wconv_kernel(
    const float* __restrict__ Wq, const float* __restrict__ Wk,
    const float* __restrict__ Wv, const float* __restrict__ Wo,
    unsigned short* __restrict__ W3T, unsigned short* __restrict__ WoT) {
  const int base = blockIdx.x * 2048;
#pragma unroll
  for (int p = 0; p < 8; p++) {
    const int idx = base + p * 256 + threadIdx.x;
    if (idx < 196608) {
      const int m = idx >> 14;           // 0..11
      const int rem = idx & 16383;
      const int c = rem >> 6, d = rem & 63;
      const int h = m / 3, kind = m - h * 3;
      const float* W = kind == 0 ? Wq : kind == 1 ? Wk : Wv;
      float v = W[h * 16384 + rem];
      if (kind == 0) v *= SCALE_Q_;
      W3T[(h * 192 + kind * 64 + d) * 256 + c] = f2bf(v);
    } else {
      const int widx = idx - 196608;     // < 65536
      const int k = widx >> 8, n = widx & 255;
      WoT[n * 256 + k] = f2bf(Wo[widx]);
    }
  }
}

// ---------------------------------------------------------------------------
// Kernel 3 (MFMA): q/k/v projections.  q16,k16: [bh][n][64]; vT16: [bh][64][N]
// 64-row tiles, grid (128, H) = 512 blocks (2/CU). Wave w owns 16 rows.
// ---------------------------------------------------------------------------
__global__ __launch_bounds__(256) void qkv_kernel(
    const unsigned short* __restrict__ h16, const unsigned short* __restrict__ W3T,
    const float* __restrict__ bq, const float* __restrict__ bk,
    const float* __restrict__ bv,
    unsigned short* __restrict__ q16, unsigned short* __restrict__ k16,
    unsigned short* __restrict__ vT16) {
  const int rt = blockIdx.x;
  const int hh = blockIdx.y;
  const int t = threadIdx.x;
  const int w = t >> 6, lane = t & 63, c = lane & 15, quad = lane >> 4;
  __shared__ unsigned short Hs[64 * 64];    // 8 KB
  __shared__ unsigned short Bs[192 * 64];   // 24 KB
  const int row0 = rt * 64;

  f32x4 acc[12];
#pragma unroll
  for (int nt = 0; nt < 12; nt++) acc[nt] = (f32x4){0.f, 0.f, 0.f, 0.f};

  for (int kt = 0; kt < C_; kt += 64) {
    __syncthreads();
#pragma unroll
    for (int p = 0; p < 2; p++) {
      const int e = t + p * 256;
      const int row = e >> 3, ch = e & 7;
      *(bf16x8*)&Hs[row * 64 + ((ch ^ (row & 7)) * 8)] =
          *(const bf16x8*)&h16[(size_t)(row0 + row) * C_ + kt + ch * 8];
    }
#pragma unroll
    for (int p = 0; p < 6; p++) {
      const int e = t + p * 256;
      const int row = e >> 3, ch = e & 7;
      *(bf16x8*)&Bs[row * 64 + ((ch ^ (row & 7)) * 8)] =
          *(const bf16x8*)&W3T[(size_t)(hh * 192 + row) * C_ + kt + ch * 8];
    }
    __syncthreads();
#pragma unroll
    for (int kh = 0; kh < 2; kh++) {
      const int i = w * 16 + c;
      bf16x8 a = *(const bf16x8*)&Hs[i * 64 + (((kh * 4 + quad) ^ (i & 7)) * 8)];
#pragma unroll
      for (int nt = 0; nt < 12; nt++) {
        const int n = nt * 16 + c;
        bf16x8 b = *(const bf16x8*)&Bs[n * 64 + (((kh * 4 + quad) ^ (n & 7)) * 8)];
        acc[nt] = MFMA32(a, b, acc[nt]);
      }
    }
  }
#pragma unroll
  for (int nt = 0; nt < 12; nt++) {
    const int kind = nt >> 2;
    const int col = (nt & 3) * 16 + c;
    const float bias = kind == 0 ? bq[hh * 64 + col] * SCALE_Q_
                     : kind == 1 ? bk[hh * 64 + col] : bv[hh * 64 + col];
#pragma unroll
    for (int r = 0; r < 4; r++) {
      const int gr = row0 + w * 16 + quad * 4 + r;
      const int b = gr >> 12, n = gr & (N_ - 1);
      const size_t bh = (size_t)(b * H_ + hh);
      const unsigned short val = f2bf(acc[nt][r] + bias);
      if (kind == 0)      q16[(bh * N_ + n) * DH_ + col] = val;
      else if (kind == 1) k16[(bh * N_ + n) * DH_ + col] = val;
      else                vT16[(bh * DH_ + col) * N_ + n] = val;
    }
  }
}

// ---------------------------------------------------------------------------
// Kernel 4 (MFMA): l_j = sum_i exp2(s~_ij); vT16 *= 1/l in place.
// R19: R18 + doubled per-round ILP (latency rule).
//   - Wave stages 32 i-rows/round (4 glls, 4KB), rounds 64->32. Per-round
//     work (16 MFMA + 32 exp ~500cyc) now exceeds the L2 round trip, so the
//     depth-1 prefetch covers latency even at 8 waves/CU.
//   - Ring-2 double buffer, counted vmcnt(4) — attnout's exact proven
//     pattern. Wave-private bufs -> ZERO barriers in the main loop.
//   - Same proven swizzle/fragment formulas as R18 (seg bases ≡ 0 mod 8,
//     so ch = sl ^ rl is unchanged).
// grid 512 (bh = blk&7, 64 j-cols) x 256 thr, LB(256,2): VGPR ~90 no spill,
// LDS 32KB+1.3KB -> 2 blocks/CU, 8 waves/CU.
// ---------------------------------------------------------------------------
__global__ __launch_bounds__(256, 2) void colstats_kernel(
    const unsigned short* __restrict__ q16, const unsigned short* __restrict__ k16,
    unsigned short* __restrict__ vT16) {
  const int blk = blockIdx.x;
  const int bh = blk & 7;
  const int j0 = (blk >> 3) * 64;
  const int t = threadIdx.x;
  const int w = t >> 6, lane = t & 63, c = lane & 15, quad = lane >> 4;
  // Ring-2 wave-private Q bufs: buf p at p*8192 u16, wave w at +w*2048.
  // Per round per wave: 32 rows x 64 d, swizzle slot = ch ^ (row&7).
  __shared__ __align__(16) unsigned short Qb[2 * 8192];   // 32 KB
  __shared__ float Lp[4][64];
  __shared__ float ilv[64];

  // K A-frags for 64 j: rows j0 + jb*16 + c, k-halves 0/32.  32 VGPRs.
  bf16x8 ka[4][2];
#pragma unroll
  for (int jb = 0; jb < 4; jb++) {
    const size_t kb = ((size_t)bh * N_ + j0 + jb * 16 + c) * DH_;
    ka[jb][0] = *(const bf16x8*)&k16[kb + quad * 8];
    ka[jb][1] = *(const bf16x8*)&k16[kb + 32 + quad * 8];
  }

  // Pre-swizzled gll source: lane l -> row_l = l>>3 (0..7), slot = l&7,
  // content chunk ch = slot ^ row_l (all seg bases are multiples of 8).
  const int rl = lane >> 3, sl = lane & 7;
  const unsigned short* gQ =
      q16 + ((size_t)bh * N_ + w * 32 + rl) * DH_ + ((sl ^ rl) * 8);
  const int woff = w * 2048;           // wave's u16 offset within a buffer

  f32x4 lsum[4];
#pragma unroll
  for (int jb = 0; jb < 4; jb++) lsum[jb] = (f32x4){0.f, 0.f, 0.f, 0.f};

  // Prologue: stage round 0 (4 glls in flight).
#pragma unroll
  for (int s = 0; s < 4; s++)
    GLL16(gQ + s * (8 * DH_), Qb + woff + s * 512);
  gQ += 128 * DH_;

  for (int r2 = 0; r2 < 32; r2 += 2) {
#pragma unroll
    for (int hf = 0; hf < 2; hf++) {     // literal buf indices after unroll
      const int cur = hf, nxt = hf ^ 1;
      // Prefetch next round into buf[nxt] (free: wave-private, consumed
      // last round). Final round over-reads adjacent allocated workspace.
#pragma unroll
      for (int s = 0; s < 4; s++)
        GLL16(gQ + s * (8 * DH_), Qb + nxt * 8192 + woff + s * 512);
      gQ += 128 * DH_;
      // Wave-private: wait own 4 oldest (round r landed); 4 newer in flight.
      asm volatile("s_waitcnt vmcnt(4)" ::: "memory");
      const unsigned short* Qs = Qb + cur * 8192 + woff;
#pragma unroll
      for (int u = 0; u < 2; u++) {      // two 16-i subtiles per round
        bf16x8 qf0 = *(const bf16x8*)&Qs[u * 1024 + c * 64 + ((quad ^ (c & 7)) * 8)];
        bf16x8 qf1 = *(const bf16x8*)&Qs[u * 1024 + c * 64 + (((4 + quad) ^ (c & 7)) * 8)];
#pragma unroll
        for (int jb = 0; jb < 4; jb++) {
          f32x4 s = {0.f, 0.f, 0.f, 0.f};
          s = MFMA32(ka[jb][0], qf0, s);
          s = MFMA32(ka[jb][1], qf1, s);
#pragma unroll
          for (int r = 0; r < 4; r++) lsum[jb][r] += FAST_EXP2(s[r]);
        }
      }
    }
  }
  // Reduce over the 16 c-lanes (i-rows), then over 4 waves via LDS.
#pragma unroll
  for (int jb = 0; jb < 4; jb++) {
#pragma unroll
    for (int r = 0; r < 4; r++) {
      float s = lsum[jb][r];
      s += __shfl_xor(s, 1); s += __shfl_xor(s, 2);
      s += __shfl_xor(s, 4); s += __shfl_xor(s, 8);
      if (c == 0) Lp[w][jb * 16 + quad * 4 + r] = s;
    }
  }
  __syncthreads();   // full drain: also retires the tail in-flight glls
  if (t < 64)
    ilv[t] = 1.0f / (Lp[0][t] + Lp[1][t] + Lp[2][t] + Lp[3][t]);
  __syncthreads();
  // Scale this block's private 64-col vT16 slice in place: V~ = invl_j * V
  {
    const int d = t >> 2, chb = t & 3;
#pragma unroll
    for (int cc = 0; cc < 2; cc++) {
      const int ch = chb + cc * 4;
      const size_t addr = ((size_t)bh * DH_ + d) * N_ + j0 + ch * 8;
      bf16x8 v = *(const bf16x8*)&vT16[addr];
#pragma unroll
      for (int jj = 0; jj < 8; jj++)
        v[jj] = (short)f2bf(bf2f((unsigned short)v[jj]) * ilv[ch * 8 + jj]);
      *(bf16x8*)&vT16[addr] = v;
    }
  }
}

// ---------------------------------------------------------------------------
// Kernel 5 (MFMA): O[i,d] = sum_j exp2(s~_ij) * V~[j,d]
// R14 staging (gll double-buffer, counted vmcnt(4), raw barriers, setprio) +
// R15 x2 unroll (literal LDS bases). Proven 43.5us.
// grid 512 x 512 thr (8 waves), launch_bounds(512,4) -> 16 waves/CU.
// ---------------------------------------------------------------------------
__global__ __launch_bounds__(512, 4) void attnout_kernel(
    const unsigned short* __restrict__ q16, const unsigned short* __restrict__ k16,
    const unsigned short* __restrict__ vT16, unsigned short* __restrict__ ob16) {
  const int blk = blockIdx.x;
  const int bh = blk & 7;
  const int bb = bh >> 2, hh = bh & 3;
  const int i0 = (blk >> 3) * 64;
  const int t = threadIdx.x;
  const int w = t >> 6, lane = t & 63, c = lane & 15, quad = lane >> 4;
  const int iw = w >> 2;           // 0..1: 32-i half
  const int jw = w & 3;            // 0..3: 32-j window of the 128-j stage

  // Double buffer: buf b at u16 offset b*16384: Ks [128 j][64 d] | Vs [64 d][128 j]
  __shared__ __align__(16) char smem[65536];
  unsigned short* S16 = (unsigned short*)smem;
  float* Rf = (float*)smem;        // epilogue reduce: 4 x 8KB regions

  // Q B-frags: rows i = i0 + iw*32 + ib*16 + c
  bf16x8 qa[2][2];
#pragma unroll
  for (int ib = 0; ib < 2; ib++) {
    const size_t qb = ((size_t)bh * N_ + i0 + iw * 32 + ib * 16 + c) * DH_;
    qa[ib][0] = *(const bf16x8*)&q16[qb + quad * 8];
    qa[ib][1] = *(const bf16x8*)&q16[qb + 32 + quad * 8];
  }

  // Pre-swizzled gll source addresses (rule #21: linear LDS dest, inverse-
  // swizzled global source, swizzled read).
  const int krow  = w * 16 + (lane >> 3);
  const int kch   = (lane & 7) ^ (((krow >> 2) & 7) ^ (krow & 3));
  const int krow2 = krow + 8;
  const int kch2  = (lane & 7) ^ (((krow2 >> 2) & 7) ^ (krow2 & 3));
  const unsigned short* gK  = k16 + ((size_t)bh * N_ + krow ) * DH_ + kch  * 8;
  const unsigned short* gK2 = k16 + ((size_t)bh * N_ + krow2) * DH_ + kch2 * 8;
  const int vd   = w * 8 + (lane >> 4);
  const int vch  = (lane & 15) ^ (vd & 15);
  const int vd2  = vd + 4;
  const int vch2 = (lane & 15) ^ (vd2 & 15);
  const unsigned short* gV  = vT16 + ((size_t)bh * DH_ + vd ) * N_ + vch  * 8;
  const unsigned short* gV2 = vT16 + ((size_t)bh * DH_ + vd2) * N_ + vch2 * 8;
  const int ldsKo = w * 1024;          // u16 offset of wave's K seg in buffer
  const int ldsVo = 8192 + w * 1024;   // u16 offset of wave's V seg in buffer

  f32x4 of[2][4];
#pragma unroll
  for (int ib = 0; ib < 2; ib++)
#pragma unroll
    for (int dt = 0; dt < 4; dt++) of[ib][dt] = (f32x4){0.f, 0.f, 0.f, 0.f};

  // Prologue: stage tile 0 into buf0 (4 glls -> vmcnt outstanding = 4).
  GLL16(gK,  S16 + ldsKo);       GLL16(gK2, S16 + ldsKo + 512);
  GLL16(gV,  S16 + ldsVo);       GLL16(gV2, S16 + ldsVo + 512);
  gK += 128 * DH_; gK2 += 128 * DH_; gV += 128; gV2 += 128;

  for (int jt = 0; jt < N_; jt += 256) {
#pragma unroll
    for (int half = 0; half < 2; half++) {   // half -> literal cur after unroll
      const int cur = half, nxt = half ^ 1;
      GLL16(gK,  S16 + nxt * 16384 + ldsKo);
      GLL16(gK2, S16 + nxt * 16384 + ldsKo + 512);
      GLL16(gV,  S16 + nxt * 16384 + ldsVo);
      GLL16(gV2, S16 + nxt * 16384 + ldsVo + 512);
      gK += 128 * DH_; gK2 += 128 * DH_; gV += 128; gV2 += 128;
      // Counted wait: 4 newest (buf[nxt]) stay in flight; buf[cur]'s landed.
      asm volatile("s_waitcnt vmcnt(4)" ::: "memory");
      asm volatile("s_barrier" ::: "memory");
      const unsigned short* Ks = S16 + cur * 16384;
      const unsigned short* Vs = S16 + cur * 16384 + 8192;

      // Permuted K A-frags, window jw: m=c -> j-local jw*32 + 8*(c>>2)+s*4+(c&3)
      bf16x8 kf[2][2];
#pragma unroll
      for (int s = 0; s < 2; s++) {
        const int jr = jw * 32 + ((c >> 2) * 8) + s * 4 + (c & 3);
        const int swz = ((jr >> 2) & 7) ^ (jr & 3);
        kf[s][0] = *(const bf16x8*)&Ks[jr * 64 + ((quad ^ swz) * 8)];
        kf[s][1] = *(const bf16x8*)&Ks[jr * 64 + (((4 + quad) ^ swz) * 8)];
      }
      // V B-frags: B[n=d][k=jj] = V~T[d][jw*32 + quad*8 + jj]
      bf16x8 vf[4];
#pragma unroll
      for (int dt = 0; dt < 4; dt++) {
        const int d = dt * 16 + c;
        vf[dt] = *(const bf16x8*)&Vs[d * 128 + (((jw * 4 + quad) ^ (d & 15)) * 8)];
      }

      __builtin_amdgcn_s_setprio(1);
#pragma unroll
      for (int ib = 0; ib < 2; ib++) {
        f32x4 s0 = {0.f, 0.f, 0.f, 0.f}, s1 = {0.f, 0.f, 0.f, 0.f};
        s0 = MFMA32(kf[0][0], qa[ib][0], s0);
        s0 = MFMA32(kf[0][1], qa[ib][1], s0);
        s1 = MFMA32(kf[1][0], qa[ib][0], s1);
        s1 = MFMA32(kf[1][1], qa[ib][1], s1);
        i32x4 pi;
        pi[0] = pack2bf(FAST_EXP2(s0[0]), FAST_EXP2(s0[1]));
        pi[1] = pack2bf(FAST_EXP2(s0[2]), FAST_EXP2(s0[3]));
        pi[2] = pack2bf(FAST_EXP2(s1[0]), FAST_EXP2(s1[1]));
        pi[3] = pack2bf(FAST_EXP2(s1[2]), FAST_EXP2(s1[3]));
        bf16x8 pf = *(bf16x8*)&pi;
#pragma unroll
        for (int dt = 0; dt < 4; dt++)
          of[ib][dt] = MFMA32(pf, vf[dt], of[ib][dt]);
      }
      __builtin_amdgcn_s_setprio(0);
      asm volatile("s_barrier" ::: "memory");
    }
  }

  // Tree reduce over the 4 jw-waves per i-half (disjoint j). Buffers dead.
  __syncthreads();
  if (jw >= 2) {
    float* dst = Rf + (iw * 2 + (jw - 2)) * 2048;
#pragma unroll
    for (int ib = 0; ib < 2; ib++)
#pragma unroll
      for (int dt = 0; dt < 4; dt++)
        *(f32x4*)&dst[lane * 32 + (((ib * 4 + dt) ^ (lane & 7)) * 4)] = of[ib][dt];
  }
  __syncthreads();
  if (jw < 2) {
    const float* src = Rf + (iw * 2 + jw) * 2048;
#pragma unroll
    for (int ib = 0; ib < 2; ib++)
#pragma unroll
      for (int dt = 0; dt < 4; dt++)
        of[ib][dt] += *(const f32x4*)&src[lane * 32 + (((ib * 4 + dt) ^ (lane & 7)) * 4)];
  }
  __syncthreads();
  if (jw == 1) {
    float* dst = Rf + iw * 2048;
#pragma unroll
    for (int ib = 0; ib < 2; ib++)
#pragma unroll
      for (int dt = 0; dt < 4; dt++)
        *(f32x4*)&dst[lane * 32 + (((ib * 4 + dt) ^ (lane & 7)) * 4)] = of[ib][dt];
  }
  __syncthreads();
  if (jw == 0) {
    const float* src = Rf + iw * 2048;
#pragma unroll
    for (int ib = 0; ib < 2; ib++)
#pragma unroll
      for (int dt = 0; dt < 4; dt++) {
        of[ib][dt] += *(const f32x4*)&src[lane * 32 + (((ib * 4 + dt) ^ (lane & 7)) * 4)];
#pragma unroll
        for (int r = 0; r < 4; r++)
          ob16[((size_t)bb * N_ + i0 + iw * 32 + ib * 16 + quad * 4 + r) * C_ +
               hh * DH_ + dt * 16 + c] = f2bf(of[ib][dt][r]);
      }
  }
}

// ---------------------------------------------------------------------------
// Kernel 6 (MFMA): out = o @ Wo + bo  (fp32 out).
// grid (256 rowtiles of 32, 2 col-halves of 128) = 512 blocks -> 2 blocks/CU.
// ---------------------------------------------------------------------------
__global__ __launch_bounds__(256) void outproj_kernel(
    const unsigned short* __restrict__ ob16, const unsigned short* __restrict__ WoT,
    const float* __restrict__ bo, float* __restrict__ out) {
  const int rt = blockIdx.x;
  const int ch2 = blockIdx.y;
  const int t = threadIdx.x;
  const int w = t >> 6, lane = t & 63, c = lane & 15, quad = lane >> 4;
  __shared__ unsigned short As[32 * 64];    // 4 KB
  __shared__ unsigned short Bs[128 * 64];   // 16 KB

  f32x4 acc[2][2];
#pragma unroll
  for (int mt = 0; mt < 2; mt++)
#pragma unroll
    for (int nt = 0; nt < 2; nt++) acc[mt][nt] = (f32x4){0.f, 0.f, 0.f, 0.f};

  for (int kt = 0; kt < C_; kt += 64) {
    __syncthreads();
    {
      const int row = t >> 3, ch = t & 7;
      *(bf16x8*)&As[row * 64 + ((ch ^ (row & 7)) * 8)] =
          *(const bf16x8*)&ob16[((size_t)rt * 32 + row) * C_ + kt + ch * 8];
    }
#pragma unroll
    for (int p = 0; p < 4; p++) {
      const int e = t + p * 256;
      const int row = e >> 3, ch = e & 7;
      *(bf16x8*)&Bs[row * 64 + ((ch ^ (row & 7)) * 8)] =
          *(const bf16x8*)&WoT[(size_t)(ch2 * 128 + row) * C_ + kt + ch * 8];
    }
    __syncthreads();
#pragma unroll
    for (int kh = 0; kh < 2; kh++) {
      bf16x8 a[2];
#pragma unroll
      for (int mt = 0; mt < 2; mt++) {
        const int i = mt * 16 + c;
        a[mt] = *(const bf16x8*)&As[i * 64 + (((kh * 4 + quad) ^ (i & 7)) * 8)];
      }
#pragma unroll
      for (int nt = 0; nt < 2; nt++) {
        const int n = w * 32 + nt * 16 + c;
        bf16x8 b = *(const bf16x8*)&Bs[n * 64 + (((kh * 4 + quad) ^ (n & 7)) * 8)];
        acc[0][nt] = MFMA32(a[0], b, acc[0][nt]);
        acc[1][nt] = MFMA32(a[1], b, acc[1][nt]);
      }
    }
  }
#pragma unroll
  for (int mt = 0; mt < 2; mt++)
#pragma unroll
    for (int nt = 0; nt < 2; nt++) {
      const int col = ch2 * 128 + w * 32 + nt * 16 + c;
      const float bias = bo[col];
#pragma unroll
      for (int r = 0; r < 4; r++)
        out[((size_t)rt * 32 + mt * 16 + quad * 4 + r) * C_ + col] = acc[mt][nt][r] + bias;
    }
}

// ---------------------------------------------------------------------------
extern "C" void kernel_launch(void* const* d_in, const int* in_sizes, int n_in,
                              void* d_out, int out_size, void* d_ws, size_t ws_size,
                              hipStream_t stream) {
  const float* x    = (const float*)d_in[0];
  const float* pos  = (const float*)d_in[1];
  const float* Wq   = (const float*)d_in[2];
  const float* bq   = (const float*)d_in[3];
  const float* Wk   = (const float*)d_in[4];
  const float* bk   = (const float*)d_in[5];
  const float* Wv   = (const float*)d_in[6];
  const float* bv   = (const float*)d_in[7];
  const float* Wo   = (const float*)d_in[8];
  const float* bo   = (const float*)d_in[9];
  const float* ln_g = (const float*)d_in[10];
  const float* ln_b = (const float*)d_in[11];
  float* out = (float*)d_out;

  // Workspace (u16): h16|q16|k16|vT16|ob16 (2M each) | W3T 196608 | WoT 65536
  const size_t SZ = (size_t)B_ * N_ * C_;   // 2097152
  unsigned short* h16  = (unsigned short*)d_ws;
  unsigned short* q16  = h16 + SZ;
  unsigned short* k16  = q16 + SZ;
  unsigned short* vT16 = k16 + SZ;
  unsigned short* ob16 = vT16 + SZ;
  unsigned short* W3T  = ob16 + SZ;
  unsigned short* WoT  = W3T + (size_t)H_ * 192 * 256;

  ln_kernel<<<B_ * N_ / 4, 256, 0, stream>>>(x, pos, ln_g, ln_b, h16);
  wconv_kernel<<<128, 256, 0, stream>>>(Wq, Wk, Wv, Wo, W3T, WoT);
  qkv_kernel<<<dim3(128, H_), 256, 0, stream>>>(h16, W3T, bq, bk, bv, q16, k16, vT16);
  colstats_kernel<<<512, 256, 0, stream>>>(q16, k16, vT16);
  attnout_kernel<<<512, 512, 0, stream>>>(q16, k16, vT16, ob16);
  outproj_kernel<<<dim3(256, 2), 256, 0, stream>>>(ob16, WoT, bo, out);
}